// Round 1
// baseline (106.683 us; speedup 1.0000x reference)
//
#include <hip/hip_runtime.h>
#include <math.h>

// NoiseGenerator: out[n] = HP(LP(noise))[n] * envelope[n] * gain
//   LP: y[n] = (1-c_lp)*x[n] + c_lp*y[n-1]
//   HP: z[n] = c_hp*(z[n-1] + y[n] - y[n-1])   (y[-1] = 0)
//   env[n] = (1 - exp(-t/attack)) * exp(-t/decay),  t = n/(N-1)
//
// Parallelization: per-thread contiguous chunks with adaptive warm-up.
// Coefficients are clamped to <= 0.99, so state influence decays below
// 1e-12 within W = ceil(-27.63/ln(cmax)) <= 2749 samples. Each thread
// runs the recurrence from zero state starting W samples before its
// chunk; truncation error ~1e-12 << 1.56e-4 threshold. Warm-up reads
// overlap neighboring chunks -> served from L1/L2, not extra HBM.

#define BLOCK 128
#define GRID  256   // 32768 threads -> chunk = 128 @ N = 4194304

__global__ __launch_bounds__(BLOCK) void noisegen_kernel(
    const float* __restrict__ params,
    const float* __restrict__ noise,
    float* __restrict__ out,
    int n, int chunk)
{
    // clamped parameters (wave-uniform; 5-float broadcast load, L2-cached)
    float attack = fmaxf(params[0], 1e-7f);
    float decay  = fmaxf(params[1], 1e-7f);
    float c_lp   = fminf(fmaxf(params[2], 1e-7f), 0.99f);
    float c_hp   = fminf(fmaxf(params[3], 1e-7f), 0.99f);
    float gain   = fmaxf(params[4], 1e-7f);

    int tid = blockIdx.x * blockDim.x + threadIdx.x;
    long long g0 = (long long)tid * (long long)chunk;
    if (g0 >= (long long)n) return;
    int gend = (int)((g0 + chunk < (long long)n) ? (g0 + chunk) : (long long)n);

    // adaptive warm-up length: cmax^W <= 1e-12  (cmax <= 0.99 -> W <= 2749)
    float cmax = fmaxf(c_lp, c_hp);
    int W = (int)ceilf(-27.631f / logf(cmax));
    W = min(max(W, 4), 4096);
    int gs = (int)((g0 - W > 0) ? (g0 - W) : 0LL);
    int gmain = (int)g0;

    float omc = 1.0f - c_lp;
    float y = 0.0f, yprev = 0.0f, z = 0.0f;

    // warm-up: run recurrence, no output
    for (int i = gs; i < gmain; ++i) {
        float x = noise[i];
        y = fmaf(c_lp, y, omc * x);
        z = c_hp * (z + (y - yprev));
        yprev = y;
    }

    float inv_nm1 = 1.0f / (float)(n - 1);
    float ia = -1.0f / attack;
    float id = -1.0f / decay;

    // main chunk: recurrence + envelope + store
    for (int i = gmain; i < gend; ++i) {
        float x = noise[i];
        y = fmaf(c_lp, y, omc * x);
        z = c_hp * (z + (y - yprev));
        yprev = y;
        float t = (float)i * inv_nm1;
        float env = (1.0f - __expf(t * ia)) * __expf(t * id);
        out[i] = z * env * gain;
    }
}

extern "C" void kernel_launch(void* const* d_in, const int* in_sizes, int n_in,
                              void* d_out, int out_size, void* d_ws, size_t ws_size,
                              hipStream_t stream) {
    const float* params = (const float*)d_in[0];
    const float* noise  = (const float*)d_in[1];
    float* out = (float*)d_out;
    int n = in_sizes[1];
    int total_threads = GRID * BLOCK;
    int chunk = (n + total_threads - 1) / total_threads;
    noisegen_kernel<<<GRID, BLOCK, 0, stream>>>(params, noise, out, n, chunk);
}

// Round 2
// 83.492 us; speedup vs baseline: 1.2778x; 1.2778x over previous
//
#include <hip/hip_runtime.h>
#include <math.h>

// NoiseGenerator: out[n] = HP(LP(noise))[n] * env[n] * gain
//   LP: y[n] = (1-c_lp)*x[n] + c_lp*y[n-1]
//   HP: z[n] = c_hp*(z[n-1] + y[n] - y[n-1])
//   env[n] = (1 - exp(-t/attack)) * exp(-t/decay), t = n/(N-1)
//
// R2: LDS-staged version. Round-1 kernel had 64-way address divergence on
// both loads and stores (per-thread contiguous chunks -> lanes stride 512B).
// Now: block stages a contiguous 8192-sample tile (+ warm-up halo) into LDS
// with coalesced float4 loads, runs the serial recurrence out of LDS
// (pad 1 word/32 -> 2-way bank aliasing only, free), writes outputs in
// place, then stores coalesced float4.
//
// Warm-up: coefficients clamped <= 0.99; state influence decays below
// ~1e-7 within W = ceil(16.12/-ln(cmax)) <= 1600 samples. Truncation error
// ~1e-7 << 1.56e-4 threshold. Block 0's negative halo = zeros (exact).

#define BLOCK 128
#define CHUNK 64
#define SAMP  (BLOCK * CHUNK)          // 8192 samples per block
#define WMAX  1600                     // warm-up cap (mult of 32)
#define TWORDS (SAMP + WMAX)           // 9792 staged words max
#define LDSW  (TWORDS + TWORDS / 32)   // +1 pad word per 32 -> 10098 (~40.4KB)

__device__ __forceinline__ int pidx(int i) { return i + (i >> 5); }

__global__ __launch_bounds__(BLOCK) void noisegen_kernel(
    const float* __restrict__ params,
    const float* __restrict__ noise,
    float* __restrict__ out, int n)
{
    __shared__ float lds[LDSW];

    // clamped parameters (wave-uniform)
    float attack = fmaxf(params[0], 1e-7f);
    float decay  = fmaxf(params[1], 1e-7f);
    float c_lp   = fminf(fmaxf(params[2], 1e-7f), 0.99f);
    float c_hp   = fminf(fmaxf(params[3], 1e-7f), 0.99f);
    float gain   = fmaxf(params[4], 1e-7f);

    // adaptive warm-up: cmax^W <= e^-16.12 ~ 1e-7
    float cmax = fmaxf(c_lp, c_hp);
    int W = (int)ceilf(-16.12f / logf(cmax));
    W = min(max(W, 4), WMAX);
    int H = (W + 31) & ~31;            // staged halo, mult of 32

    int tid = threadIdx.x;
    int B = blockIdx.x * SAMP;         // block's first output sample
    int base = B - H;                  // first staged sample (<0 for block 0)
    int T = H + SAMP;                  // staged word count (mult of 32)

    // ---- stage [base, B+SAMP) into LDS, coalesced float4, zero-fill g<0 ----
    for (int v = tid; v < (T >> 2); v += BLOCK) {
        int i = v << 2;                // tile-local word index, mult of 4
        int g = base + i;
        float4 val = make_float4(0.f, 0.f, 0.f, 0.f);
        if (g >= 0 && g + 3 < n) {
            val = *(const float4*)(noise + g);
        }
        int p = pidx(i);               // 4 words stay contiguous (i%32 <= 28)
        lds[p] = val.x; lds[p + 1] = val.y; lds[p + 2] = val.z; lds[p + 3] = val.w;
    }
    __syncthreads();

    float omc = 1.0f - c_lp;
    float y = 0.f, yprev = 0.f, z = 0.f;
    int l0 = H + tid * CHUNK;          // tile-local start of own chunk

    // warm-up: read-only pass over [l0-W, l0)
    for (int j = l0 - W; j < l0; ++j) {
        float x = lds[pidx(j)];
        y = fmaf(c_lp, y, omc * x);
        z = c_hp * (z + (y - yprev));
        yprev = y;
    }
    __syncthreads();                   // all warm-ups done before in-place writes

    float inv_nm1 = 1.0f / (float)(n - 1);
    float ia = -1.0f / attack;
    float id = -1.0f / decay;
    int g0 = B + tid * CHUNK;

    // main pass: read own chunk, write output in place
    #pragma unroll 4
    for (int j = 0; j < CHUNK; ++j) {
        int gi = g0 + j;
        if (gi >= n) break;
        int p = pidx(l0 + j);
        float x = lds[p];
        y = fmaf(c_lp, y, omc * x);
        z = c_hp * (z + (y - yprev));
        yprev = y;
        float t = (float)gi * inv_nm1;
        float env = (1.0f - __expf(t * ia)) * __expf(t * id);
        lds[p] = z * env * gain;
    }
    __syncthreads();

    // ---- coalesced float4 store ----
    for (int v = tid; v < (SAMP >> 2); v += BLOCK) {
        int i = v << 2;
        int g = B + i;
        if (g + 3 < n) {
            int p = pidx(H + i);
            *(float4*)(out + g) = make_float4(lds[p], lds[p + 1], lds[p + 2], lds[p + 3]);
        }
    }
}

extern "C" void kernel_launch(void* const* d_in, const int* in_sizes, int n_in,
                              void* d_out, int out_size, void* d_ws, size_t ws_size,
                              hipStream_t stream) {
    const float* params = (const float*)d_in[0];
    const float* noise  = (const float*)d_in[1];
    float* out = (float*)d_out;
    int n = in_sizes[1];
    int grid = (n + SAMP - 1) / SAMP;  // 512 blocks @ n = 4194304
    noisegen_kernel<<<grid, BLOCK, 0, stream>>>(params, noise, out, n);
}

// Round 3
// 78.140 us; speedup vs baseline: 1.3653x; 1.0685x over previous
//
#include <hip/hip_runtime.h>
#include <math.h>

// NoiseGenerator: out[n] = HP(LP(noise))[n] * env[n] * gain
//   LP: y[n] = a*y[n-1] + (1-a)*x[n]            (a = filter_lp)
//   HP: z[n] = b*(z[n-1] + y[n] - y[n-1])       (b = filter_hp)
//   env[n] = (1 - exp(-t/attack)) * exp(-t/decay), t = n/(N-1)
//
// R3: exact within-block parallel scan replaces per-thread serial warm-up.
// State-space: s = (y,z); s[n] = M s[n-1] + v x[n], M = [[a,0],[b(a-1),b]]
// (lower triangular -> matrix powers/products are 3 scalar FMAs).
// Per block: stage 9472 contiguous samples (8192 tile + 1280 halo) into LDS;
// 256 threads each run a 37-sample chunk from ZERO state recording end-state
// E[t]; Hillis-Steele scan (8 steps, double-buffered LDS, wave-uniform
// powers of M^37 by repeated squaring) yields each thread's exact initial
// state; second pass applies envelope and writes in place; coalesced f4 store.
// Halo truncation: cmax <= 0.99 -> cmax^1280 <= 2.6e-6 << 1.56e-4 threshold.
// Envelope: 2 expf per THREAD (geometric running product), not per sample.
// CHUNK=37 (odd): serial-phase LDS lane stride 37 -> bank (5*l+j)%32 -> 2-way
// aliasing only (free, m136); no padding needed.

#define BLOCK 256
#define CHUNK 37
#define TWORDS (BLOCK * CHUNK)      // 9472 staged words (~37.9 KB)
#define SAMP   8192                 // output samples per block
#define HALO   (TWORDS - SAMP)      // 1280 (mult of 4)

__global__ __launch_bounds__(BLOCK) void noisegen_kernel(
    const float* __restrict__ params,
    const float* __restrict__ noise,
    float* __restrict__ out, int n)
{
    __shared__ __align__(16) float xs[TWORDS];
    __shared__ float sy[2][BLOCK];
    __shared__ float sz[2][BLOCK];

    // clamped parameters (wave-uniform)
    float attack = fmaxf(params[0], 1e-7f);
    float decay  = fmaxf(params[1], 1e-7f);
    float a      = fminf(fmaxf(params[2], 1e-7f), 0.99f);
    float b      = fminf(fmaxf(params[3], 1e-7f), 0.99f);
    float gain   = fmaxf(params[4], 1e-7f);
    float omc    = 1.0f - a;

    int tid  = threadIdx.x;
    int B    = blockIdx.x * SAMP;    // block's first output sample
    int base = B - HALO;             // first staged sample (<0 for block 0)

    // ---- stage [base, base+TWORDS) into LDS, coalesced float4 ----
    for (int v = tid; v < (TWORDS >> 2); v += BLOCK) {
        int i = v << 2;
        int g = base + i;
        float4 val;
        if (g >= 0 && g + 4 <= n) {
            val = *(const float4*)(noise + g);
        } else {
            val.x = (g     >= 0 && g     < n) ? noise[g]     : 0.0f;
            val.y = (g + 1 >= 0 && g + 1 < n) ? noise[g + 1] : 0.0f;
            val.z = (g + 2 >= 0 && g + 2 < n) ? noise[g + 2] : 0.0f;
            val.w = (g + 3 >= 0 && g + 3 < n) ? noise[g + 3] : 0.0f;
        }
        *(float4*)(xs + i) = val;
    }
    __syncthreads();

    // ---- phase B: zero-state pass over own chunk -> end state E[t] ----
    int l0 = tid * CHUNK;
    float yv = 0.0f, zv = 0.0f;
    #pragma unroll 4
    for (int j = 0; j < CHUNK; ++j) {
        float x  = xs[l0 + j];
        float yn = fmaf(a, yv, omc * x);
        zv = b * (zv + (yn - yv));
        yv = yn;
    }
    sy[0][tid] = yv;
    sz[0][tid] = zv;
    __syncthreads();

    // ---- phase C: inclusive scan of states, operator s += P * s_prev ----
    // P starts at M^CHUNK, squared each step. Lower-tri (pa,pw,pb):
    //   top=pa, corner=pw, bottom=pb. Product C=A*B: ca=Aa*Ba, cb=Ab*Bb,
    //   cw=Aw*Ba+Ab*Bw. Powers of M commute.
    float ma = a, mw = b * (a - 1.0f), mb = b;            // M^1
    float pa = ma, pw = mw, pb = mb;
    // M^2, M^4
    { float qa=pa*pa, qw=pw*pa+pb*pw, qb=pb*pb; pa=qa; pw=qw; pb=qb; }
    float p4a, p4w, p4b;
    { p4a=pa*pa; p4w=pw*pa+pb*pw; p4b=pb*pb; }
    // M^8, M^16, M^32
    float ta=p4a, tw=p4w, tb=p4b;
    { float qa=ta*ta, qw=tw*ta+tb*tw, qb=tb*tb; ta=qa; tw=qw; tb=qb; }
    { float qa=ta*ta, qw=tw*ta+tb*tw, qb=tb*tb; ta=qa; tw=qw; tb=qb; }
    { float qa=ta*ta, qw=tw*ta+tb*tw, qb=tb*tb; ta=qa; tw=qw; tb=qb; }
    // M^37 = M^32 * M^4 * M^1
    { float qa=ta*p4a, qw=tw*p4a+tb*p4w, qb=tb*p4b; ta=qa; tw=qw; tb=qb; }
    { float qa=ta*ma,  qw=tw*ma +tb*mw,  qb=tb*mb;  pa=qa; pw=qw; pb=qb; }

    int cur = 0;
    for (int d = 1; d < BLOCK; d <<= 1) {
        float ny = sy[cur][tid], nz = sz[cur][tid];
        if (tid >= d) {
            float py = sy[cur][tid - d], pz = sz[cur][tid - d];
            ny = fmaf(pa, py, ny);
            nz = fmaf(pw, py, fmaf(pb, pz, nz));
        }
        sy[1 - cur][tid] = ny;
        sz[1 - cur][tid] = nz;
        cur = 1 - cur;
        // P <- P^2
        float qa = pa * pa, qw = pw * pa + pb * pw, qb = pb * pb;
        pa = qa; pw = qw; pb = qb;
        __syncthreads();
    }

    // exclusive: thread t's init = inclusive[t-1]; t=0 -> zero (halo start)
    float y0 = 0.0f, z0 = 0.0f;
    if (tid > 0) { y0 = sy[cur][tid - 1]; z0 = sz[cur][tid - 1]; }

    // ---- phase D: exact pass with envelope, write in place ----
    float inv_nm1 = 1.0f / (float)(n - 1);
    float ia = -1.0f / attack;
    float id = -1.0f / decay;
    float t0 = (float)(base + l0) * inv_nm1;
    float ea = __expf(ia * t0);          // exp(-t/attack) running product
    float ed = __expf(id * t0);          // exp(-t/decay)  running product
    float ra = __expf(ia * inv_nm1);
    float rd = __expf(id * inv_nm1);

    yv = y0; zv = z0;
    #pragma unroll 4
    for (int j = 0; j < CHUNK; ++j) {
        int li = l0 + j;
        float x  = xs[li];
        float yn = fmaf(a, yv, omc * x);
        zv = b * (zv + (yn - yv));
        yv = yn;
        if (li >= HALO) {
            float env = (1.0f - ea) * ed;
            xs[li] = zv * env * gain;
        }
        ea *= ra; ed *= rd;
    }
    __syncthreads();

    // ---- coalesced float4 store of tile region ----
    for (int v = tid; v < (SAMP >> 2); v += BLOCK) {
        int i = v << 2;
        int g = B + i;
        if (g + 4 <= n) {
            *(float4*)(out + g) = *(const float4*)(xs + HALO + i);
        } else {
            for (int c = 0; c < 4; ++c)
                if (g + c < n) out[g + c] = xs[HALO + i + c];
        }
    }
}

extern "C" void kernel_launch(void* const* d_in, const int* in_sizes, int n_in,
                              void* d_out, int out_size, void* d_ws, size_t ws_size,
                              hipStream_t stream) {
    const float* params = (const float*)d_in[0];
    const float* noise  = (const float*)d_in[1];
    float* out = (float*)d_out;
    int n = in_sizes[1];
    int grid = (n + SAMP - 1) / SAMP;   // 512 blocks @ n = 4194304
    noisegen_kernel<<<grid, BLOCK, 0, stream>>>(params, noise, out, n);
}

// Round 5
// 76.235 us; speedup vs baseline: 1.3994x; 1.0250x over previous
//
#include <hip/hip_runtime.h>
#include <math.h>

// NoiseGenerator: out[n] = HP(LP(noise))[n] * env[n] * gain
//   LP: y[n] = a*y[n-1] + (1-a)*x[n]            (a = filter_lp)
//   HP: z[n] = b*(z[n-1] + y[n] - y[n-1])       (b = filter_hp)
//   env[n] = (1 - exp(-t/attack)) * exp(-t/decay), t = n/(N-1)
//
// R4b: same as R4, with the nontemporal store cast fixed (native clang
// ext_vector_type instead of HIP_vector_type float4).
//  - State-space s=(y,z): s[n] = M s[n-1] + v x[n], M = [[a,0],[b(a-1),b]]
//    lower-triangular -> operators are 3 floats, compose = 3 FMAs.
//  - Phase B: each thread runs its 21-sample chunk from ZERO state,
//    writing the zero-state z response back into xs IN PLACE (own addrs,
//    no barrier needed), recording end-state E.
//  - Phase C: intra-wave Hillis-Steele scan via __shfl_up (6 steps,
//    operator squared each step); wave-end states through 4-entry LDS;
//    per-lane cross-wave recombine via binary composition of saved powers.
//    Barriers: 11 (R3) -> 3.
//  - Phase D (linearity): total z = z_zerostate + (M^{j+1} s0)_z; the
//    homogeneous recurrence is register-only, LDS read off the dep chain.
//  - CHUNK 21 (odd -> 2-way LDS bank aliasing only, free), SAMP 4096,
//    grid 1024: ~21.5 KB LDS -> 4 blocks/CU, 16 waves/CU during staging.
//    Halo re-reads are L3-served (16.7 MB input << 256 MB L3).
//  - Halo 1280: cmax<=0.99 -> truncation 0.99^1280 ~ 2.6e-6 << 1.56e-4.
//  - Envelope via geometric running products (2 expf/thread); exact reset
//    at global index 0 guards exp-overflow in block 0's negative prologue.

#define BLOCK 256
#define CHUNK 21
#define TWORDS (BLOCK * CHUNK)      // 5376 staged words (~21.5 KB)
#define HALO   1280
#define SAMP   (TWORDS - HALO)      // 4096 output samples per block

typedef float vfloat4 __attribute__((ext_vector_type(4)));

struct Op { float a, w, b; };       // [[a,0],[w,b]]
__device__ __forceinline__ Op opmul(Op A, Op B) {   // A*B
    Op C;
    C.a = A.a * B.a;
    C.w = fmaf(A.w, B.a, A.b * B.w);
    C.b = A.b * B.b;
    return C;
}

__global__ __launch_bounds__(BLOCK) void noisegen_kernel(
    const float* __restrict__ params,
    const float* __restrict__ noise,
    float* __restrict__ out, int n)
{
    __shared__ __align__(16) float xs[TWORDS];
    __shared__ float swy[4], swz[4];

    // clamped parameters (wave-uniform)
    float attack = fmaxf(params[0], 1e-7f);
    float decay  = fmaxf(params[1], 1e-7f);
    float a      = fminf(fmaxf(params[2], 1e-7f), 0.99f);
    float b      = fminf(fmaxf(params[3], 1e-7f), 0.99f);
    float gain   = fmaxf(params[4], 1e-7f);
    float omc    = 1.0f - a;

    int tid  = threadIdx.x;
    int B    = blockIdx.x * SAMP;
    int base = B - HALO;            // <0 for block 0

    // ---- stage [base, base+TWORDS) into LDS, coalesced float4 ----
    for (int v = tid; v < (TWORDS >> 2); v += BLOCK) {
        int i = v << 2;
        int g = base + i;
        vfloat4 val;
        if (g >= 0 && g + 4 <= n) {
            val = *(const vfloat4*)(noise + g);
        } else {
            val.x = (g     >= 0 && g     < n) ? noise[g]     : 0.0f;
            val.y = (g + 1 >= 0 && g + 1 < n) ? noise[g + 1] : 0.0f;
            val.z = (g + 2 >= 0 && g + 2 < n) ? noise[g + 2] : 0.0f;
            val.w = (g + 3 >= 0 && g + 3 < n) ? noise[g + 3] : 0.0f;
        }
        *(vfloat4*)(xs + i) = val;
    }
    __syncthreads();                // barrier 1

    // ---- phase B: zero-state pass, write z response in place ----
    int l0 = tid * CHUNK;
    float yv = 0.0f, zv = 0.0f;
    #pragma unroll 3
    for (int j = 0; j < CHUNK; ++j) {
        float x  = xs[l0 + j];
        float yn = fmaf(a, yv, omc * x);
        zv = b * (zv + (yn - yv));
        yv = yn;
        xs[l0 + j] = zv;            // own address; no cross-thread hazard
    }

    // ---- phase C: scan of end-states across 256 threads ----
    int lane = tid & 63, wid = tid >> 6;
    // P = M^CHUNK (21 = 16+4+1) via squaring
    Op m1 = { a, b * (a - 1.0f), b };
    Op m2 = opmul(m1, m1), m4 = opmul(m2, m2), m8 = opmul(m4, m4), m16 = opmul(m8, m8);
    Op P = opmul(opmul(m16, m4), m1);

    Op Psave[6];
    float cy = yv, cz = zv;
    #pragma unroll
    for (int k = 0; k < 6; ++k) {
        Psave[k] = P;
        int d = 1 << k;
        float py = __shfl_up(cy, d, 64);
        float pz = __shfl_up(cz, d, 64);
        if (lane >= d) {
            cy = fmaf(P.a, py, cy);
            cz = fmaf(P.w, py, fmaf(P.b, pz, cz));
        }
        P = opmul(P, P);            // after loop: P = M^(64*CHUNK) = Q
    }
    if (lane == 63) { swy[wid] = cy; swz[wid] = cz; }
    __syncthreads();                // barrier 2

    // cross-wave prefix: pref_w = sum_{u<w} Q^(w-1-u) S_u
    float pry = 0.0f, prz = 0.0f;
    for (int u = 0; u < wid; ++u) { // wave-uniform trip count
        float ny = fmaf(P.a, pry, swy[u]);
        float nz = fmaf(P.w, pry, fmaf(P.b, prz, swz[u]));
        pry = ny; prz = nz;
    }
    // exclusive intra-wave value
    float ey = __shfl_up(cy, 1, 64);
    float ez = __shfl_up(cz, 1, 64);
    if (lane == 0) { ey = 0.0f; ez = 0.0f; }
    // per-lane operator M^(CHUNK*lane) from saved powers (commuting)
    Op O = { 1.0f, 0.0f, 1.0f };
    #pragma unroll
    for (int k = 0; k < 6; ++k)
        if ((lane >> k) & 1) O = opmul(Psave[k], O);
    float y0 = fmaf(O.a, pry, ey);
    float z0 = ez + fmaf(O.w, pry, O.b * prz);

    // ---- phase D: homogeneous correction + envelope, in place ----
    float inv_nm1 = 1.0f / (float)(n - 1);
    float ia = -1.0f / attack;
    float id = -1.0f / decay;
    float t0 = (float)(base + l0) * inv_nm1;
    float ea = __expf(ia * t0);     // exp(-t/attack) running product
    float ed = __expf(id * t0);     // exp(-t/decay)
    float ra = __expf(ia * inv_nm1);
    float rd = __expf(id * inv_nm1);

    float yh = y0, zh = z0;
    #pragma unroll 3
    for (int j = 0; j < CHUNK; ++j) {
        float yn = a * yh;
        zh = b * (zh + (yn - yh));
        yh = yn;
        int li = l0 + j;
        if (base + li == 0) { ea = 1.0f; ed = 1.0f; }  // exact t=0 reset
        if (li >= HALO) {
            float env = (1.0f - ea) * ed;
            xs[li] = (xs[li] + zh) * (env * gain);
        }
        ea *= ra; ed *= rd;
    }
    __syncthreads();                // barrier 3

    // ---- coalesced nontemporal float4 store ----
    for (int v = tid; v < (SAMP >> 2); v += BLOCK) {
        int i = v << 2;
        int g = B + i;
        if (g + 4 <= n) {
            vfloat4 val = *(const vfloat4*)(xs + HALO + i);
            __builtin_nontemporal_store(val, (vfloat4*)(out + g));
        } else {
            for (int c = 0; c < 4; ++c)
                if (g + c < n) out[g + c] = xs[HALO + i + c];
        }
    }
}

extern "C" void kernel_launch(void* const* d_in, const int* in_sizes, int n_in,
                              void* d_out, int out_size, void* d_ws, size_t ws_size,
                              hipStream_t stream) {
    const float* params = (const float*)d_in[0];
    const float* noise  = (const float*)d_in[1];
    float* out = (float*)d_out;
    int n = in_sizes[1];
    int grid = (n + SAMP - 1) / SAMP;   // 1024 blocks @ n = 4194304
    noisegen_kernel<<<grid, BLOCK, 0, stream>>>(params, noise, out, n);
}